// Round 8
// baseline (194.029 us; speedup 1.0000x reference)
//
#include <hip/hip_runtime.h>
#include <hip/hip_bf16.h>

#define Tcnt 32768      // B*S
#define Gn   2
#define Vn   320
#define Dn   128
#define DIMK 512
#define GV   640        // G*V
#define RB   64         // rows per fused block
#define NCAND 12

typedef __attribute__((ext_vector_type(8))) short bf16x8;
typedef __attribute__((ext_vector_type(8))) ushort u16x8;
typedef __attribute__((ext_vector_type(4))) float f32x4;

__device__ inline ushort f2bf(float x) {
    unsigned u = __float_as_uint(x);
    return (ushort)((u + 0x7fffu + ((u >> 16) & 1u)) >> 16);   // RNE
}
__device__ inline ushort nbf(float x) {            // native cvt (RNE), enables cvt_pk
    __hip_bfloat16 h = __float2bfloat16(x);
    return *reinterpret_cast<ushort*>(&h);
}
__device__ inline bf16x8 cvt8(float4 a, float4 b) {
    u16x8 o;
    o[0]=nbf(a.x); o[1]=nbf(a.y); o[2]=nbf(a.z); o[3]=nbf(a.w);
    o[4]=nbf(b.x); o[5]=nbf(b.y); o[6]=nbf(b.z); o[7]=nbf(b.w);
    return (bf16x8)o;
}

// ---- prep: W [512,640] fp32 -> Wt2 fragment-ordered bf16 -------------------------
// Wt2 layout: [(gnb 0..39)][ks 0..15][lane 0..63][8]; element (lane=(Q<<4)|c16, s):
//   W[ks*32 + Q*8 + s][gnb*16 + c16]
__global__ __launch_bounds__(256) void prep_wt2(
    const float* __restrict__ W, ushort* __restrict__ Wt2)
{
    __shared__ ushort Ls[512][17];
    const int gnb = blockIdx.x;             // 0..39
    const int colbase = gnb * 16;
    const int t = threadIdx.x;
    const int c = t & 15, kq = t >> 4;
    for (int r = 0; r < 32; ++r) {
        int k = r * 16 + kq;
        Ls[k][c] = f2bf(W[(size_t)k * GV + colbase + c]);
    }
    __syncthreads();
    #pragma unroll
    for (int ii = 0; ii < 4; ++ii) {
        int ls = ii * 256 + t;
        int ks = ls >> 6, lane = ls & 63;
        int c16 = lane & 15, Q = lane >> 4;
        u16x8 o;
        #pragma unroll
        for (int s = 0; s < 8; ++s)
            o[s] = Ls[ks * 32 + Q * 8 + s][c16];
        *(u16x8*)(Wt2 + (((size_t)gnb * 16 + ks) * 64 + lane) * 8) = o;
    }
}

// ------- fused: barrier-free reg GEMM(64x320) + softmax + argmax(+fixup) + gather ---
__global__ __launch_bounds__(512, 2) void fused_vq_kernel(
    const float*  __restrict__ hs,    // [T, 512] fp32
    const ushort* __restrict__ Wt2,   // fragment-ordered bf16 (L2-resident)
    const float*  __restrict__ W,     // [512, 640] fp32 (fixup only)
    const float*  __restrict__ bias,  // [640]
    const float*  __restrict__ gum,   // [T*G, 320]
    const float*  __restrict__ cv,    // [640, 128]
    float* __restrict__ out,          // [T, 256]
    float* __restrict__ dist)         // [T*G, 320]
{
    __shared__ float4 part[RB][4];
    __shared__ int    s_cnt[RB];
    __shared__ int    s_col[RB][NCAND];
    __shared__ float  s_s[RB][NCAND];
    __shared__ float  s_gm[RB][NCAND];
    __shared__ int    s_bidx[RB];
    __shared__ float  s_mxs[RB];

    const int tid = threadIdx.x, w = tid >> 6, lane = tid & 63;
    const int Q = lane >> 4, c16 = lane & 15;
    const int wrow = (w >> 2) * 32;       // row sub-block (0 / 32)
    const int wq = w & 3;                 // column quarter
    const int wn = wq * 80;

    const int bid = blockIdx.x;
    const int swz = (bid & 7) * 128 + (bid >> 3);   // XCD chunking; (t,g) pair same XCD
    const int g = swz & 1;
    const size_t t0 = (size_t)(swz >> 1) * RB;

    if (tid < RB) s_cnt[tid] = 0;

    // A: per-lane direct loads (rows wrow+c16, wrow+16+c16; k-slice Q*8..Q*8+7)
    const float* a0p = hs + (t0 + wrow + c16) * DIMK + Q * 8;
    const float* a1p = a0p + 16 * DIMK;
    // B: fragment-ordered, 1KB coalesced per (j,ks)
    const ushort* bb = Wt2 + ((size_t)(g * 20 + wq * 5) * 16 * 64) * 8 + lane * 8;

    f32x4 acc[10];
    #pragma unroll
    for (int j = 0; j < 10; ++j) acc[j] = (f32x4){0.f, 0.f, 0.f, 0.f};

    // ---- K loop: 16 steps BK=32, NO barriers, NO LDS — pure reg/ILP pipeline ----
    #pragma unroll
    for (int ks = 0; ks < 16; ++ks) {
        float4 x0 = *(const float4*)(a0p + ks * 32);
        float4 x1 = *(const float4*)(a0p + ks * 32 + 4);
        float4 y0 = *(const float4*)(a1p + ks * 32);
        float4 y1 = *(const float4*)(a1p + ks * 32 + 4);
        bf16x8 af0 = cvt8(x0, x1);
        bf16x8 af1 = cvt8(y0, y1);
        #pragma unroll
        for (int j = 0; j < 5; ++j) {
            bf16x8 bv = *(const bf16x8*)(bb + ((size_t)j * 16 + ks) * 512);
            acc[j]     = __builtin_amdgcn_mfma_f32_16x16x32_bf16(af0, bv, acc[j],     0, 0, 0);
            acc[5 + j] = __builtin_amdgcn_mfma_f32_16x16x32_bf16(af1, bv, acc[5 + j], 0, 0, 0);
        }
    }

    // ---- bias ----
    #pragma unroll
    for (int j = 0; j < 5; ++j) {
        float bbv = bias[g * Vn + wn + j * 16 + c16];
        #pragma unroll
        for (int qq = 0; qq < 4; ++qq) { acc[j][qq] += bbv; acc[5 + j][qq] += bbv; }
    }

    __syncthreads();   // also covers s_cnt init

    const float MARGIN = 0.0625f;

    // ---- phase 1: per-row quarter-stats + candidate pool ----
    #pragma unroll
    for (int i = 0; i < 2; ++i) {
      #pragma unroll
      for (int qr = 0; qr < 4; ++qr) {
        int row = wrow + i * 16 + Q * 4 + qr;       // C/D layout row
        size_t r2 = (t0 + row) * 2 + g;
        const float* gr = gum + r2 * Vn + wn;
        float lg[5], sv[5];
        float mxl = -1e30f, mxs = -1e30f; int bi = 0;
        #pragma unroll
        for (int j = 0; j < 5; ++j) {
            lg[j] = acc[i * 5 + j][qr];
            sv[j] = lg[j] + gr[j * 16 + c16];
            mxl = fmaxf(mxl, lg[j]);
            if (sv[j] > mxs) { mxs = sv[j]; bi = wn + j * 16 + c16; }
        }
        #pragma unroll
        for (int off = 1; off < 16; off <<= 1) {
            mxl = fmaxf(mxl, __shfl_xor(mxl, off));
            float os = __shfl_xor(mxs, off); int ob = __shfl_xor(bi, off);
            if (os > mxs || (os == mxs && ob < bi)) { mxs = os; bi = ob; }
        }
        float sum = 0.f;
        #pragma unroll
        for (int j = 0; j < 5; ++j) sum += __expf(lg[j] - mxl);
        #pragma unroll
        for (int off = 1; off < 16; off <<= 1) sum += __shfl_xor(sum, off);

        float thr = mxs - MARGIN;
        #pragma unroll
        for (int j = 0; j < 5; ++j) {
            if (sv[j] >= thr) {
                int pos = atomicAdd(&s_cnt[row], 1);
                if (pos < NCAND) {
                    s_col[row][pos] = wn + j * 16 + c16;
                    s_s[row][pos]   = sv[j];
                    s_gm[row][pos]  = sv[j] - lg[j];
                }
            }
        }
        if (c16 == 0) part[row][wq] = (float4){mxl, sum, mxs, __int_as_float(bi)};
      }
    }
    __syncthreads();

    // ---- phase 2: merge quarters, write dist, final approx argmax ----
    #pragma unroll
    for (int i = 0; i < 2; ++i) {
      #pragma unroll
      for (int qr = 0; qr < 4; ++qr) {
        int row = wrow + i * 16 + Q * 4 + qr;
        size_t r2 = (t0 + row) * 2 + g;
        float4 p0 = part[row][0], p1 = part[row][1], p2 = part[row][2], p3 = part[row][3];
        float mxl_f = fmaxf(fmaxf(p0.x, p1.x), fmaxf(p2.x, p3.x));
        float sum_f = p0.y * __expf(p0.x - mxl_f) + p1.y * __expf(p1.x - mxl_f)
                    + p2.y * __expf(p2.x - mxl_f) + p3.y * __expf(p3.x - mxl_f);
        float inv = 1.0f / sum_f;
        float* dr = dist + r2 * Vn + wn;
        #pragma unroll
        for (int j = 0; j < 5; ++j)
            dr[j * 16 + c16] = __expf(acc[i * 5 + j][qr] - mxl_f) * inv;
        if (wq == 0 && c16 == 0) {
            float ms = p0.z; int mi = __float_as_int(p0.w);
            if (p1.z > ms || (p1.z == ms && __float_as_int(p1.w) < mi)) { ms = p1.z; mi = __float_as_int(p1.w); }
            if (p2.z > ms || (p2.z == ms && __float_as_int(p2.w) < mi)) { ms = p2.z; mi = __float_as_int(p2.w); }
            if (p3.z > ms || (p3.z == ms && __float_as_int(p3.w) < mi)) { ms = p3.z; mi = __float_as_int(p3.w); }
            s_mxs[row] = ms; s_bidx[row] = mi;
        }
      }
    }
    __syncthreads();

    // ---- fixup: exact fp32 recompute for rows with >1 candidate in GLOBAL margin ----
    for (int ui = 0; ui < 8; ++ui) {
        int u = w * 8 + ui;
        int c = s_cnt[u]; if (c > NCAND) c = NCAND;
        float thr = s_mxs[u] - MARGIN;
        int nf = 0;
        for (int j = 0; j < c; ++j) nf += (s_s[u][j] >= thr) ? 1 : 0;
        if (nf > 1) {
            size_t t = t0 + u;
            const float* hr = hs + t * DIMK;
            float4 h0 = *(const float4*)(hr + lane * 8);
            float4 h1 = *(const float4*)(hr + lane * 8 + 4);
            float hv[8] = {h0.x, h0.y, h0.z, h0.w, h1.x, h1.y, h1.z, h1.w};
            float best = -1e30f; int bv2 = 1 << 30;
            for (int j = 0; j < c; ++j) {
                if (s_s[u][j] < thr) continue;
                int v = s_col[u][j];
                int gcol = g * Vn + v;
                const float* wc = W + gcol;
                float p = 0.f;
                #pragma unroll
                for (int i2 = 0; i2 < 8; ++i2)
                    p = fmaf(hv[i2], wc[(size_t)(lane * 8 + i2) * GV], p);
                #pragma unroll
                for (int off = 1; off < 64; off <<= 1) p += __shfl_xor(p, off);
                float se = p + bias[gcol] + s_gm[u][j];
                if (se > best || (se == best && v < bv2)) { best = se; bv2 = v; }
            }
            if (lane == 0) s_bidx[u] = bv2;
        }
    }
    __syncthreads();

    // ---- gather codevectors -> out ----
    for (int ui = 0; ui < 8; ++ui) {
        int u = w * 8 + ui;
        size_t t = t0 + u;
        int b2 = s_bidx[u];
        const float2* cvr = (const float2*)(cv + ((size_t)(g * Vn + b2)) * Dn);
        float2 val = cvr[lane];
        *(float2*)(out + t * (Gn * Dn) + g * Dn + lane * 2) = val;
    }
}

extern "C" void kernel_launch(void* const* d_in, const int* in_sizes, int n_in,
                              void* d_out, int out_size, void* d_ws, size_t ws_size,
                              hipStream_t stream) {
    const float* hs  = (const float*)d_in[0];  // [8,4096,512]
    const float* W   = (const float*)d_in[1];  // [512,640]
    const float* b   = (const float*)d_in[2];  // [640]
    const float* cv  = (const float*)d_in[3];  // [640,128]
    const float* gum = (const float*)d_in[4];  // [65536,320]

    float* out  = (float*)d_out;                      // [32768, 256]
    float* dist = out + (size_t)Tcnt * (Gn * Dn);     // [65536, 320]
    ushort* Wt2 = (ushort*)d_ws;                      // 640 KB fragment-ordered

    prep_wt2<<<40, 256, 0, stream>>>(W, Wt2);
    fused_vq_kernel<<<(Tcnt / RB) * Gn, 512, 0, stream>>>(hs, Wt2, W, b, gum, cv, out, dist);
}

// Round 9
// 92.331 us; speedup vs baseline: 2.1015x; 2.1015x over previous
//
#include <hip/hip_runtime.h>

#define Tcnt 32768      // B*S
#define Gn   2
#define Vn   320
#define Dn   128
#define DIMK 512
#define GV   640        // G*V
#define RB   128        // rows per fused block
#define NCAND 8

typedef __attribute__((ext_vector_type(8))) short bf16x8;
typedef __attribute__((ext_vector_type(4))) ushort u16x4;
typedef __attribute__((ext_vector_type(4))) float f32x4;

__device__ inline ushort f2bf(float x) {
    unsigned u = __float_as_uint(x);
    return (ushort)((u + 0x7fffu + ((u >> 16) & 1u)) >> 16);   // RNE
}

#define AS1(p) ((const __attribute__((address_space(1))) void*)(p))
#define AS3(p) ((__attribute__((address_space(3))) void*)(p))

// ---------------- prep: W [512,640] fp32 -> Wt [640,512] bf16 (transposed) ----------
__global__ __launch_bounds__(256) void prep_wt(
    const float* __restrict__ W, ushort* __restrict__ Wt)
{
    __shared__ ushort Ls[64][72];
    int t = blockIdx.x;                     // 0..79
    int n0 = (t % 10) * 64, k0 = (t / 10) * 64;
    int ln = threadIdx.x & 63, kq = threadIdx.x >> 6;
    #pragma unroll
    for (int kk = 0; kk < 16; ++kk) {
        int k = kq * 16 + kk;
        Ls[k][ln] = f2bf(W[(size_t)(k0 + k) * GV + n0 + ln]);
    }
    __syncthreads();
    #pragma unroll
    for (int nn = 0; nn < 16; ++nn) {
        int n = kq * 16 + nn;
        Wt[(size_t)(n0 + n) * DIMK + k0 + ln] = Ls[ln][n];
    }
}

// ------- fused: GEMM(128x320) + bias + softmax + gumbel-argmax(+fixup) + gather -----
// 1024 threads / 16 waves; wave-tile 16x160; LDS: GEMM staging UNIONed with epilogue.
__global__ __launch_bounds__(1024, 4) void fused_vq_kernel(
    const float*  __restrict__ hs,    // [T, 512] fp32
    const ushort* __restrict__ Wt,    // [640, 512] bf16 transposed
    const float*  __restrict__ W,     // [512, 640] fp32 (fixup only)
    const float*  __restrict__ bias,  // [640]
    const float*  __restrict__ gum,   // [T*G, 320]
    const float*  __restrict__ cv,    // [640, 128]
    float* __restrict__ out,          // [T, 256]
    float* __restrict__ dist)         // [T*G, 320]
{
    union SMem {
        struct { ushort As[2][RB * 32]; ushort Bs[2][Vn * 32]; } gm;  // 16 + 40 KB
        struct {
            float4 part[RB][2];       // {mxl, sum, mxs, idx} per col-half
            int    cnt[RB];
            int    col[RB][NCAND];
            float  sc[RB][NCAND];
            float  gmv[RB][NCAND];
            int    bidx[RB];
            float  mxs[RB];
        } ep;                          // ~17.5 KB
    };
    __shared__ SMem U;

    const int tid = threadIdx.x, w = tid >> 6, lane = tid & 63;
    const int Q = lane >> 4, c16 = lane & 15;
    const int wm = (w >> 1) * 16, wn = (w & 1) * 160, half = w & 1;

    const int bid = blockIdx.x;
    const int swz = (bid & 7) * 64 + (bid >> 3);    // XCD chunking (512 % 8 == 0)
    const int g = swz & 1;                          // (t,g0),(t,g1) adjacent on same XCD
    const size_t t0 = (size_t)(swz >> 1) * RB;

    // ---- A staging map: thread -> (row, phys 4-float chunk); source pre-swizzled ----
    const int arow_s = tid >> 3, pc = tid & 7;
    const int lq = (pc >> 1) ^ ((arow_s >> 1) & 3);
    const int lc = lq * 2 + (pc & 1);
    const float* asrc = hs + (t0 + arow_s) * DIMK + lc * 4;
    const ushort* wtg = Wt + (size_t)g * Vn * DIMK;

    auto stageB = [&](int buf, int k0) {
        {
            int s = tid;
            int n = s >> 2, pq = s & 3, lqq = pq ^ ((n >> 1) & 3);
            __builtin_amdgcn_global_load_lds(
                AS1(wtg + (size_t)n * DIMK + k0 + lqq * 8),
                AS3(&U.gm.Bs[buf][s * 8]), 16, 0, 0);
        }
        if (tid < 256) {
            int s = 1024 + tid;
            int n = s >> 2, pq = s & 3, lqq = pq ^ ((n >> 1) & 3);
            __builtin_amdgcn_global_load_lds(
                AS1(wtg + (size_t)n * DIMK + k0 + lqq * 8),
                AS3(&U.gm.Bs[buf][s * 8]), 16, 0, 0);
        }
    };
    auto writeA = [&](int buf, float4 v) {
        u16x4 o;
        o[0] = f2bf(v.x); o[1] = f2bf(v.y); o[2] = f2bf(v.z); o[3] = f2bf(v.w);
        *(u16x4*)&U.gm.As[buf][tid * 4] = o;
    };

    // ---- prologue: stage step 0, prefetch step 1 into regs ----
    float4 areg0 = *(const float4*)(asrc);
    stageB(0, 0);
    float4 areg1 = *(const float4*)(asrc + 32);
    writeA(0, areg0);
    __syncthreads();

    f32x4 acc[10];
    #pragma unroll
    for (int j = 0; j < 10; ++j) acc[j] = (f32x4){0.f, 0.f, 0.f, 0.f};

    // ---- K loop: 16 steps BK=32, dbuf B (gll), depth-2 A reg prefetch ----
    #pragma unroll
    for (int ks = 0; ks < 16; ++ks) {
        if (ks + 2 < 16) {
            if ((ks & 1) == 0) areg0 = *(const float4*)(asrc + (ks + 2) * 32);
            else               areg1 = *(const float4*)(asrc + (ks + 2) * 32);
        }
        if (ks + 1 < 16) stageB((ks + 1) & 1, (ks + 1) * 32);

        const ushort* Ab = U.gm.As[ks & 1];
        const ushort* Bb = U.gm.Bs[ks & 1];
        const int ar = wm + c16;
        bf16x8 af = *(const bf16x8*)&Ab[(ar * 4 + (Q ^ ((ar >> 1) & 3))) * 8];
        #pragma unroll
        for (int j = 0; j < 10; ++j) {
            int n = wn + j * 16 + c16;
            bf16x8 bv = *(const bf16x8*)&Bb[(n * 4 + (Q ^ ((n >> 1) & 3))) * 8];
            acc[j] = __builtin_amdgcn_mfma_f32_16x16x32_bf16(af, bv, acc[j], 0, 0, 0);
        }
        if (ks + 1 < 16) writeA((ks + 1) & 1, ((ks + 1) & 1) ? areg1 : areg0);
        __syncthreads();
    }
    // gm staging LDS now dead; ep may be used after the next barrier.

    // ---- bias (regs only) ----
    #pragma unroll
    for (int j = 0; j < 10; ++j) {
        float bb = bias[g * Vn + wn + j * 16 + c16];
        acc[j][0] += bb; acc[j][1] += bb; acc[j][2] += bb; acc[j][3] += bb;
    }

    if (tid < RB) U.ep.cnt[tid] = 0;
    __syncthreads();

    const float MARGIN = 0.0625f;

    // ---- phase 1: per-row half-stats + candidate pool ----
    #pragma unroll
    for (int qr = 0; qr < 4; ++qr) {
        int row = wm + Q * 4 + qr;                 // local row (C/D layout)
        size_t r2 = (t0 + row) * 2 + g;
        const float* gr = gum + r2 * Vn + wn;
        float sv[10];
        float mxl = -1e30f, mxs = -1e30f; int bi = 0;
        #pragma unroll
        for (int j = 0; j < 10; ++j) {
            float lg = acc[j][qr];
            float gu = gr[j * 16 + c16];
            float s = lg + gu; sv[j] = s;
            mxl = fmaxf(mxl, lg);
            if (s > mxs) { mxs = s; bi = wn + j * 16 + c16; }
        }
        #pragma unroll
        for (int off = 1; off < 16; off <<= 1) {
            mxl = fmaxf(mxl, __shfl_xor(mxl, off));
            float os = __shfl_xor(mxs, off); int ob = __shfl_xor(bi, off);
            if (os > mxs || (os == mxs && ob < bi)) { mxs = os; bi = ob; }
        }
        float sum = 0.f;
        #pragma unroll
        for (int j = 0; j < 10; ++j) sum += __expf(acc[j][qr] - mxl);
        #pragma unroll
        for (int off = 1; off < 16; off <<= 1) sum += __shfl_xor(sum, off);

        float thr = mxs - MARGIN;
        #pragma unroll
        for (int j = 0; j < 10; ++j) {
            if (sv[j] >= thr) {
                int pos = atomicAdd(&U.ep.cnt[row], 1);
                if (pos < NCAND) {
                    U.ep.col[row][pos] = wn + j * 16 + c16;
                    U.ep.sc[row][pos]  = sv[j];
                    U.ep.gmv[row][pos] = sv[j] - acc[j][qr];
                }
            }
        }
        if (c16 == 0)
            U.ep.part[row][half] = (float4){mxl, sum, mxs, __int_as_float(bi)};
    }
    __syncthreads();

    // ---- phase 2: combine halves, write dist, final approx argmax ----
    #pragma unroll
    for (int qr = 0; qr < 4; ++qr) {
        int row = wm + Q * 4 + qr;
        size_t r2 = (t0 + row) * 2 + g;
        float4 mine = U.ep.part[row][half];
        float4 oth  = U.ep.part[row][half ^ 1];
        float mxl_f = fmaxf(mine.x, oth.x);
        float sum_f = mine.y * __expf(mine.x - mxl_f) + oth.y * __expf(oth.x - mxl_f);
        float inv = 1.0f / sum_f;
        float* dr = dist + r2 * Vn + wn;
        #pragma unroll
        for (int j = 0; j < 10; ++j)
            dr[j * 16 + c16] = __expf(acc[j][qr] - mxl_f) * inv;
        if (half == 0 && c16 == 0) {
            float ms = mine.z; int mi = __float_as_int(mine.w);
            float os = oth.z;  int oi = __float_as_int(oth.w);
            if (os > ms || (os == ms && oi < mi)) { ms = os; mi = oi; }
            U.ep.mxs[row] = ms; U.ep.bidx[row] = mi;
        }
    }
    __syncthreads();

    // ---- fixup: exact fp32 recompute for near-tie rows (8 units/wave) ----
    for (int ui = 0; ui < 8; ++ui) {
        int u = w * 8 + ui;
        int c = U.ep.cnt[u]; if (c > NCAND) c = NCAND;
        float thr = U.ep.mxs[u] - MARGIN;
        int nf = 0;
        for (int j = 0; j < c; ++j) nf += (U.ep.sc[u][j] >= thr) ? 1 : 0;
        if (nf > 1) {
            size_t t = t0 + u;
            const float* hr = hs + t * DIMK;
            float4 h0 = *(const float4*)(hr + lane * 8);
            float4 h1 = *(const float4*)(hr + lane * 8 + 4);
            float hv[8] = {h0.x, h0.y, h0.z, h0.w, h1.x, h1.y, h1.z, h1.w};
            float best = -1e30f; int bv2 = 1 << 30;
            for (int j = 0; j < c; ++j) {
                if (U.ep.sc[u][j] < thr) continue;
                int v = U.ep.col[u][j];
                int gcol = g * Vn + v;
                const float* wc = W + gcol;
                float p = 0.f;
                #pragma unroll
                for (int i = 0; i < 8; ++i)
                    p = fmaf(hv[i], wc[(size_t)(lane * 8 + i) * GV], p);
                #pragma unroll
                for (int off = 1; off < 64; off <<= 1) p += __shfl_xor(p, off);
                float se = p + bias[gcol] + U.ep.gmv[u][j];
                if (se > best || (se == best && v < bv2)) { best = se; bv2 = v; }
            }
            if (lane == 0) U.ep.bidx[u] = bv2;
        }
    }
    __syncthreads();

    // ---- gather codevectors -> out ----
    for (int ui = 0; ui < 8; ++ui) {
        int u = w * 8 + ui;
        size_t t = t0 + u;
        int b = U.ep.bidx[u];
        const float2* cvr = (const float2*)(cv + ((size_t)(g * Vn + b)) * Dn);
        float2 val = cvr[lane];
        *(float2*)(out + t * (Gn * Dn) + g * Dn + lane * 2) = val;
    }
}

extern "C" void kernel_launch(void* const* d_in, const int* in_sizes, int n_in,
                              void* d_out, int out_size, void* d_ws, size_t ws_size,
                              hipStream_t stream) {
    const float* hs  = (const float*)d_in[0];  // [8,4096,512]
    const float* W   = (const float*)d_in[1];  // [512,640]
    const float* b   = (const float*)d_in[2];  // [640]
    const float* cv  = (const float*)d_in[3];  // [640,128]
    const float* gum = (const float*)d_in[4];  // [65536,320]

    float* out  = (float*)d_out;                      // [32768, 256]
    float* dist = out + (size_t)Tcnt * (Gn * Dn);     // [65536, 320]
    ushort* Wt  = (ushort*)d_ws;                      // [640, 512] bf16 = 640 KB

    prep_wt<<<80, 256, 0, stream>>>(W, Wt);
    fused_vq_kernel<<<(Tcnt / RB) * Gn, 1024, 0, stream>>>(hs, Wt, W, b, gum, cv, out, dist);
}